// Round 7
// baseline (1678.598 us; speedup 1.0000x reference)
//
#include <hip/hip_runtime.h>
#include <hip/hip_bf16.h>
#include <cmath>
#include <cstddef>

// Problem constants (from reference)
#define NN 100000
#define HH 128
#define EE 1600000
#define NH (NN * HH)
#define ALPHA_C 0.1f
#define THETA_C 0.5f
#define EPS_C 1e-5f

constexpr int SCAN_B = 256;
constexpr int NBLK = (NN + SCAN_B - 1) / SCAN_B;   // 391 scan blocks
constexpr int ABST = 136;   // LDS A-tile stride in bf16 (128 + 8 pad -> b128-clean)

typedef __attribute__((ext_vector_type(8))) short s8v;   // 8 bf16 (4 VGPRs)
typedef __attribute__((ext_vector_type(4))) float f4v;   // 4 fp32 acc

#define MFMA16(a, b, c) __builtin_amdgcn_mfma_f32_16x16x32_bf16(a, b, c, 0, 0, 0)

// fp32 -> bf16 RNE bits, and back
__device__ __forceinline__ unsigned short f2bf(float f) {
    unsigned u = __float_as_uint(f);
    u += 0x7fffu + ((u >> 16) & 1u);
    return (unsigned short)(u >> 16);
}
__device__ __forceinline__ float bf2f(unsigned short h) {
    return __uint_as_float((unsigned)h << 16);
}

// ---------------------------------------------------------------------------
__global__ __launch_bounds__(256) void zero_int_k(int* __restrict__ p, int n) {
    int i = blockIdx.x * 256 + threadIdx.x;
    if (i < n) p[i] = 0;
}
__global__ __launch_bounds__(256) void zero_f4_k(float4* __restrict__ p, int n4) {
    int i = blockIdx.x * 256 + threadIdx.x;
    if (i < n4) p[i] = float4{0.f, 0.f, 0.f, 0.f};
}

// ---------------------------------------------------------------------------
// Index dtype detection: int64 (values < 2^31) -> every odd 32-bit word is 0.
__global__ void detect_idx64(const int* __restrict__ p, int* __restrict__ flag) {
    int any = 0;
    for (int i = 0; i < 64; ++i) any |= p[2 * i + 1];
    *flag = (any == 0) ? 1 : 0;
}

__device__ __forceinline__ int load_idx(const void* p, int e, int is64) {
    return is64 ? (int)((const long long*)p)[e] : ((const int*)p)[e];
}

// ---------------------------------------------------------------------------
// CSR build
__global__ __launch_bounds__(256) void hist_k(
    const void* __restrict__ dstp, const int* __restrict__ flag,
    int* __restrict__ hist)
{
    int e = blockIdx.x * 256 + threadIdx.x;
    if (e >= EE) return;
    atomicAdd(&hist[load_idx(dstp, e, *flag)], 1);
}

__global__ __launch_bounds__(SCAN_B) void scan1_k(
    const int* __restrict__ hist, int* __restrict__ incl, int* __restrict__ bsum)
{
    __shared__ int sh[SCAN_B];
    int t = threadIdx.x;
    int i = blockIdx.x * SCAN_B + t;
    int v = (i < NN) ? hist[i] : 0;
    sh[t] = v;
    __syncthreads();
    for (int off = 1; off < SCAN_B; off <<= 1) {
        int x = (t >= off) ? sh[t - off] : 0;
        __syncthreads();
        sh[t] += x;
        __syncthreads();
    }
    if (i < NN) incl[i] = sh[t];
    if (t == SCAN_B - 1) bsum[blockIdx.x] = sh[t];
}

__global__ __launch_bounds__(512) void scan2_k(int* __restrict__ bsum) {
    __shared__ int sh[512];
    int t = threadIdx.x;
    sh[t] = (t < NBLK) ? bsum[t] : 0;
    __syncthreads();
    for (int off = 1; off < 512; off <<= 1) {
        int x = (t >= off) ? sh[t - off] : 0;
        __syncthreads();
        sh[t] += x;
        __syncthreads();
    }
    if (t < NBLK) bsum[t] = sh[t];
}

__global__ __launch_bounds__(SCAN_B) void scan3_k(
    const int* __restrict__ hist, const int* __restrict__ incl,
    const int* __restrict__ bsum, int* __restrict__ row_ptr,
    int* __restrict__ cursor)
{
    int b = blockIdx.x;
    int i = b * SCAN_B + threadIdx.x;
    if (i < NN) {
        int ex = incl[i] - hist[i] + (b > 0 ? bsum[b - 1] : 0);
        row_ptr[i] = ex;
        cursor[i] = ex;
    }
    if (i == 0) row_ptr[NN] = EE;
}

__global__ __launch_bounds__(256) void fill_k(
    const void* __restrict__ srcp, const void* __restrict__ dstp,
    const int* __restrict__ flag, int* __restrict__ cursor,
    int* __restrict__ sorted_src)
{
    int e = blockIdx.x * 256 + threadIdx.x;
    if (e >= EE) return;
    int is64 = *flag;
    int d = load_idx(dstp, e, is64);
    int pos = atomicAdd(&cursor[d], 1);
    sorted_src[pos] = load_idx(srcp, e, is64);
}

// ---------------------------------------------------------------------------
// CSR gather, 2 edges/iter, optional fused BN+ReLU (stats -> scale/shift)
__global__ __launch_bounds__(256) void gather_k(
    const float* __restrict__ z, const int* __restrict__ row_ptr,
    const int* __restrict__ sorted_src,
    const float* __restrict__ stats,    // [256]: sum, sumsq; null = no BN
    const float* __restrict__ gamma, const float* __restrict__ beta,
    float* __restrict__ msg)
{
    int node = blockIdx.x * 4 + (threadIdx.x >> 6);
    if (node >= NN) return;
    int lane = threadIdx.x & 63;
    int half = lane >> 5;
    int c4 = lane & 31;

    const bool bn = (stats != nullptr);
    float4 sc = {1.f, 1.f, 1.f, 1.f}, sh = {0.f, 0.f, 0.f, 0.f};
    if (bn) {
        const float invN = 1.f / (float)NN;
        float4 s  = ((const float4*)stats)[c4];
        float4 s2 = ((const float4*)(stats + 128))[c4];
        float4 g  = ((const float4*)gamma)[c4];
        float4 b  = ((const float4*)beta)[c4];
        float m, var;
        m = s.x * invN; var = s2.x * invN - m * m;
        sc.x = rsqrtf(var + EPS_C) * g.x; sh.x = b.x - m * sc.x;
        m = s.y * invN; var = s2.y * invN - m * m;
        sc.y = rsqrtf(var + EPS_C) * g.y; sh.y = b.y - m * sc.y;
        m = s.z * invN; var = s2.z * invN - m * m;
        sc.z = rsqrtf(var + EPS_C) * g.z; sh.z = b.z - m * sc.z;
        m = s.w * invN; var = s2.w * invN - m * m;
        sc.w = rsqrtf(var + EPS_C) * g.w; sh.w = b.w - m * sc.w;
    }

    int e0 = row_ptr[node], e1 = row_ptr[node + 1];
    float4 acc = {0.f, 0.f, 0.f, 0.f};
    for (int e = e0 + half; e < e1; e += 2) {
        int s = sorted_src[e];
        float4 v = ((const float4*)(z + (size_t)s * HH))[c4];
        if (bn) {
            v.x = fmaxf(0.f, v.x * sc.x + sh.x);
            v.y = fmaxf(0.f, v.y * sc.y + sh.y);
            v.z = fmaxf(0.f, v.z * sc.z + sh.z);
            v.w = fmaxf(0.f, v.w * sc.w + sh.w);
        }
        acc.x += v.x; acc.y += v.y; acc.z += v.z; acc.w += v.w;
    }
    acc.x += __shfl_down(acc.x, 32);
    acc.y += __shfl_down(acc.y, 32);
    acc.z += __shfl_down(acc.z, 32);
    acc.w += __shfl_down(acc.w, 32);
    if (half == 0)
        ((float4*)(msg + (size_t)node * HH))[c4] = acc;
}

// ---------------------------------------------------------------------------
// Weight prep: build W' = (i==0 ? W_in : (1-bl)I + bl*conv_W[i-1]),
// split hi/lo bf16, store TRANSPOSED [c][k] for MFMA B-frag b128 loads.
__global__ __launch_bounds__(256) void prep_w_t(
    const float* __restrict__ W_in, const float* __restrict__ conv_W,
    unsigned short* __restrict__ WtH, unsigned short* __restrict__ WtL)
{
    int i = blockIdx.y;                          // 0..5
    int idx = blockIdx.x * 256 + threadIdx.x;    // k*128+c
    int k = idx >> 7, c = idx & 127;
    float v;
    if (i == 0) {
        v = W_in[idx];
    } else {
        float bl = logf(THETA_C / (float)i + 1.f);
        v = bl * conv_W[(size_t)(i - 1) * 16384 + idx] + ((k == c) ? (1.f - bl) : 0.f);
    }
    unsigned short h = f2bf(v);
    size_t o = (size_t)i * 16384 + c * 128 + k;
    WtH[o] = h;
    WtL[o] = f2bf(v - bf2f(h));
}

// W_jk [512][128] -> split hi/lo, transposed [c][512]
__global__ __launch_bounds__(256) void prep_wjk_t(
    const float* __restrict__ Wjk,
    unsigned short* __restrict__ WtH, unsigned short* __restrict__ WtL)
{
    int idx = blockIdx.x * 256 + threadIdx.x;    // k*128+c, k<512
    int k = idx >> 7, c = idx & 127;
    float v = Wjk[idx];
    unsigned short h = f2bf(v);
    size_t o = (size_t)c * 512 + k;
    WtH[o] = h;
    WtL[o] = f2bf(v - bf2f(h));
}

// ---------------------------------------------------------------------------
// MFMA GEMM (split-bf16, fp32-accurate): out = (cA*src0 + cB*src1) @ W' + bias
// A split hi/lo in LDS; W' pre-split/transposed bf16 in global (L2-hot).
// D = Ah@Wh + Al@Wh + Ah@Wl  (error ~2^-16 relative).
// Frag layouts (m89/m120-verified): A[m=lane&15][k=quad*8+j],
// B[k=quad*8+j][n=lane&15], C/D col=lane&15, row=quad*4+reg.
__global__ __launch_bounds__(256) void gemm128(
    const float* __restrict__ src0, const float* __restrict__ src1,
    float cA, float cB,
    const unsigned short* __restrict__ WtH, const unsigned short* __restrict__ WtL,
    const float* __restrict__ bias, float* __restrict__ out,
    float* __restrict__ statsp, int nrows)
{
    __shared__ __align__(16) unsigned short AsH[64 * ABST];
    __shared__ __align__(16) unsigned short AsL[64 * ABST];
    const int t = threadIdx.x;
    const int lane = t & 63, wv = t >> 6;
    const int m = lane & 15, quad = lane >> 4;
    const int row0 = blockIdx.x * 64;
    const bool useB = (cB != 0.f);

    // stage A: split hi/lo bf16 into LDS [row][k], stride 136
#pragma unroll
    for (int i = 0; i < 8; ++i) {
        int idx = i * 256 + t;          // 0..2047
        int r = idx >> 5, k4 = idx & 31;
        float4 v = {0.f, 0.f, 0.f, 0.f};
        if (row0 + r < nrows) {
            float4 a = ((const float4*)(src0 + (size_t)(row0 + r) * HH))[k4];
            if (useB) {
                float4 b = ((const float4*)(src1 + (size_t)(row0 + r) * HH))[k4];
                v.x = cA * a.x + cB * b.x; v.y = cA * a.y + cB * b.y;
                v.z = cA * a.z + cB * b.z; v.w = cA * a.w + cB * b.w;
            } else {
                v.x = cA * a.x; v.y = cA * a.y; v.z = cA * a.z; v.w = cA * a.w;
            }
        }
        ushort4 hh, ll;
        hh.x = f2bf(v.x); ll.x = f2bf(v.x - bf2f(hh.x));
        hh.y = f2bf(v.y); ll.y = f2bf(v.y - bf2f(hh.y));
        hh.z = f2bf(v.z); ll.z = f2bf(v.z - bf2f(hh.z));
        hh.w = f2bf(v.w); ll.w = f2bf(v.w - bf2f(hh.w));
        *(ushort4*)&AsH[r * ABST + k4 * 4] = hh;
        *(ushort4*)&AsL[r * ABST + k4 * 4] = ll;
    }
    __syncthreads();

    // A-frags for this wave's 16 rows (all 4 k-chunks, hi+lo)
    const s8v* A8h = (const s8v*)AsH;
    const s8v* A8l = (const s8v*)AsL;
    const int rl = wv * 16 + m;          // ABST/8 = 17 s8v per row
    s8v ah[4], al[4];
#pragma unroll
    for (int kc = 0; kc < 4; ++kc) {
        ah[kc] = A8h[rl * 17 + kc * 4 + quad];
        al[kc] = A8l[rl * 17 + kc * 4 + quad];
    }

    const s8v* B8h = (const s8v*)WtH;    // [c][k]: s8v idx = c*16 + kc*4 + quad
    const s8v* B8l = (const s8v*)WtL;

    f4v acc[8];
#pragma unroll
    for (int tt = 0; tt < 8; ++tt) {
        int c = tt * 16 + m;
        f4v a = {0.f, 0.f, 0.f, 0.f};
#pragma unroll
        for (int kc = 0; kc < 4; ++kc) {
            s8v bh = B8h[c * 16 + kc * 4 + quad];
            s8v bl = B8l[c * 16 + kc * 4 + quad];
            a = MFMA16(ah[kc], bh, a);
            a = MFMA16(al[kc], bh, a);
            a = MFMA16(ah[kc], bl, a);
        }
        acc[tt] = a;
    }

    // epilogue: write + optional BN sum/sumsq partials through dead LDS
    const bool doStats = (statsp != nullptr);
    __syncthreads();                     // all waves done reading As
    float* redS = (float*)AsH;           // [16][128]
    float* redQ = (float*)AsL;
#pragma unroll
    for (int tt = 0; tt < 8; ++tt) {
        int c = tt * 16 + m;
        float bb = bias ? bias[c] : 0.f;
        float s = 0.f, q = 0.f;
#pragma unroll
        for (int reg = 0; reg < 4; ++reg) {
            int r = row0 + wv * 16 + quad * 4 + reg;
            if (r < nrows) {
                float v = acc[tt][reg] + bb;
                out[(size_t)r * HH + c] = v;
                s += v; q += v * v;
            }
        }
        if (doStats) {
            redS[(wv * 4 + quad) * 128 + c] = s;
            redQ[(wv * 4 + quad) * 128 + c] = q;
        }
    }
    if (doStats) {
        __syncthreads();
        if (t < 128) {
            float s = 0.f, q = 0.f;
#pragma unroll
            for (int g = 0; g < 16; ++g) {
                s += redS[g * 128 + t];
                q += redQ[g * 128 + t];
            }
            atomicAdd(&statsp[t], s);
            atomicAdd(&statsp[128 + t], q);
        }
    }
}

// ---------------------------------------------------------------------------
// JK GEMM: out = concat(z0..z3)[N,512] @ Wjk + bjk, same split-MFMA scheme.
// WtH/WtL are [c][512] bf16. out may alias z0 (block reads own rows first).
__global__ __launch_bounds__(256) void gemm_jk(
    const float* __restrict__ z0, const float* __restrict__ z1,
    const float* __restrict__ z2, const float* __restrict__ z3,
    const unsigned short* __restrict__ WtH, const unsigned short* __restrict__ WtL,
    const float* __restrict__ bjk, float* __restrict__ out, int nrows)
{
    __shared__ __align__(16) unsigned short AsH[64 * ABST];
    __shared__ __align__(16) unsigned short AsL[64 * ABST];
    const int t = threadIdx.x;
    const int lane = t & 63, wv = t >> 6;
    const int m = lane & 15, quad = lane >> 4;
    const int row0 = blockIdx.x * 64;

    f4v acc[8];
#pragma unroll
    for (int tt = 0; tt < 8; ++tt) acc[tt] = f4v{0.f, 0.f, 0.f, 0.f};

    const s8v* B8h = (const s8v*)WtH;    // [c][512]: idx = c*64 + j*16 + kc*4 + quad
    const s8v* B8l = (const s8v*)WtL;
    const float* srcs[4] = {z0, z1, z2, z3};

    for (int j = 0; j < 4; ++j) {
        if (j) __syncthreads();
        const float* Z = srcs[j];
#pragma unroll
        for (int i = 0; i < 8; ++i) {
            int idx = i * 256 + t;
            int r = idx >> 5, k4 = idx & 31;
            float4 v = {0.f, 0.f, 0.f, 0.f};
            if (row0 + r < nrows)
                v = ((const float4*)(Z + (size_t)(row0 + r) * HH))[k4];
            ushort4 hh, ll;
            hh.x = f2bf(v.x); ll.x = f2bf(v.x - bf2f(hh.x));
            hh.y = f2bf(v.y); ll.y = f2bf(v.y - bf2f(hh.y));
            hh.z = f2bf(v.z); ll.z = f2bf(v.z - bf2f(hh.z));
            hh.w = f2bf(v.w); ll.w = f2bf(v.w - bf2f(hh.w));
            *(ushort4*)&AsH[r * ABST + k4 * 4] = hh;
            *(ushort4*)&AsL[r * ABST + k4 * 4] = ll;
        }
        __syncthreads();

        const s8v* A8h = (const s8v*)AsH;
        const s8v* A8l = (const s8v*)AsL;
        const int rl = wv * 16 + m;
        s8v ah[4], al[4];
#pragma unroll
        for (int kc = 0; kc < 4; ++kc) {
            ah[kc] = A8h[rl * 17 + kc * 4 + quad];
            al[kc] = A8l[rl * 17 + kc * 4 + quad];
        }
#pragma unroll
        for (int tt = 0; tt < 8; ++tt) {
            int c = tt * 16 + m;
            f4v a = acc[tt];
#pragma unroll
            for (int kc = 0; kc < 4; ++kc) {
                s8v bh = B8h[c * 64 + j * 16 + kc * 4 + quad];
                s8v bl = B8l[c * 64 + j * 16 + kc * 4 + quad];
                a = MFMA16(ah[kc], bh, a);
                a = MFMA16(al[kc], bh, a);
                a = MFMA16(ah[kc], bl, a);
            }
            acc[tt] = a;
        }
    }

#pragma unroll
    for (int tt = 0; tt < 8; ++tt) {
        int c = tt * 16 + m;
        float bb = bjk[c];
#pragma unroll
        for (int reg = 0; reg < 4; ++reg) {
            int r = row0 + wv * 16 + quad * 4 + reg;
            if (r < nrows)
                out[(size_t)r * HH + c] = acc[tt][reg] + bb;
        }
    }
}

// ---------------------------------------------------------------------------
extern "C" void kernel_launch(void* const* d_in, const int* in_sizes, int n_in,
                              void* d_out, int out_size, void* d_ws, size_t ws_size,
                              hipStream_t stream)
{
    const float* x       = (const float*)d_in[0];
    const float* W_in    = (const float*)d_in[1];
    const float* b_in    = (const float*)d_in[2];
    const float* conv_W  = (const float*)d_in[3];
    const float* bn_g    = (const float*)d_in[4];
    const float* bn_b    = (const float*)d_in[5];
    const float* W_jk    = (const float*)d_in[6];
    const float* b_jk    = (const float*)d_in[7];
    const void*  srcp    = d_in[8];
    const void*  dstp    = d_in[9];

    // Workspace: bf16 weight tables first (16B-aligned), then fp32 buffers.
    unsigned short* WtH   = (unsigned short*)d_ws;     // [6][128][128]
    unsigned short* WtL   = WtH + 6 * 16384;
    unsigned short* WjkTH = WtL + 6 * 16384;           // [128][512]
    unsigned short* WjkTL = WjkTH + 65536;
    float* x0     = (float*)(WjkTL + 65536);           // [N,H] z0, residual
    float* msg    = x0 + (size_t)NH;                   // [N,H]
    float* zs0    = x0 + 2 * (size_t)NH;               // z per layer; JK out
    float* zs1    = x0 + 3 * (size_t)NH;
    float* zs2    = x0 + 4 * (size_t)NH;
    float* stats3 = x0 + 5 * (size_t)NH;               // [3][256]
    int*   flag       = (int*)(stats3 + 768);
    int*   hist       = flag + 1;                      // [NN]
    int*   incl       = hist + NN;                     // [NN]
    int*   row_ptr    = incl + NN;                     // [NN+1]
    int*   cursor     = row_ptr + NN + 1;              // [NN]
    int*   bsum       = cursor + NN;                   // [NBLK]
    int*   sorted_src = bsum + NBLK + 1;               // [EE]

    const int GEMM_GRID = (NN + 63) / 64;         // 1563
    const int EDGE_GRID = (EE + 255) / 256;       // 6250
    const int NODE_GRID = (NN + 3) / 4;           // 25000

    // ---- CSR build + weight prep + stats zero (once per launch) ----
    detect_idx64<<<1, 1, 0, stream>>>((const int*)srcp, flag);
    zero_int_k<<<(NN + 255) / 256, 256, 0, stream>>>(hist, NN);
    zero_f4_k<<<1, 192, 0, stream>>>((float4*)stats3, 192);
    hist_k<<<EDGE_GRID, 256, 0, stream>>>(dstp, flag, hist);
    scan1_k<<<NBLK, SCAN_B, 0, stream>>>(hist, incl, bsum);
    scan2_k<<<1, 512, 0, stream>>>(bsum);
    scan3_k<<<NBLK, SCAN_B, 0, stream>>>(hist, incl, bsum, row_ptr, cursor);
    fill_k<<<EDGE_GRID, 256, 0, stream>>>(srcp, dstp, flag, cursor, sorted_src);
    prep_w_t<<<dim3(64, 6), 256, 0, stream>>>(W_in, conv_W, WtH, WtL);
    prep_wjk_t<<<256, 256, 0, stream>>>(W_jk, WjkTH, WjkTL);

    // ---- x0 = x @ W_in + b_in ----
    gemm128<<<GEMM_GRID, 256, 0, stream>>>(x, x, 1.f, 0.f, WtH, WtL,
                                           b_in, x0, nullptr, NN);

    const float* act = x0;
    const float* stats_cur = nullptr;
    const float* g_cur = nullptr;
    const float* b_cur = nullptr;

    for (int i = 0; i < 5; ++i) {
        gather_k<<<NODE_GRID, 256, 0, stream>>>(act, row_ptr, sorted_src,
                                                stats_cur, g_cur, b_cur, msg);

        float* zraw = (i >= 3) ? (float*)d_out : (zs0 + (size_t)i * NH);
        float* stats_next = (i < 3) ? (stats3 + (size_t)i * 256) : nullptr;
        gemm128<<<GEMM_GRID, 256, 0, stream>>>(
            msg, x0, 1.f - ALPHA_C, ALPHA_C,
            WtH + (size_t)(i + 1) * 16384, WtL + (size_t)(i + 1) * 16384,
            nullptr, zraw, stats_next, NN);
        if (i < 3) {
            act = zraw;                 // BN+ReLU fused into next gather
            stats_cur = stats_next;
            g_cur = bn_g + (size_t)i * HH;
            b_cur = bn_b + (size_t)i * HH;
        } else if (i == 3) {
            gemm_jk<<<GEMM_GRID, 256, 0, stream>>>(zs0, zs1, zs2,
                                                   (const float*)d_out,
                                                   WjkTH, WjkTL, b_jk, zs0, NN);
            act = zs0;
            stats_cur = nullptr;
            g_cur = nullptr;
            b_cur = nullptr;
        }
    }
}